// Round 1
// baseline (271.348 us; speedup 1.0000x reference)
//
#include <hip/hip_runtime.h>
#include <stdint.h>

// Problem: B=4,Q=75,C=5 -> 1500 groups; D=512; P=36. fp32 in/out.
// Round-5 theory: previous kernel was latency-serialized (VGPR-starved
// rematerialized global re-loads, VALU 7.7% / HBM 10%). This version:
// whole group resident in LDS (153 KB, 1 block/CU), single global touch
// via global_load_lds DMA (max MLP, zero VGPR cost), counted-vmcnt overlap
// of T-phase compute under R-load, all passes LDS-local.
#define NGRP 1500
#define DD   512
#define PP   36
#define DP   (DD*PP)          // 18432 floats per tensor per group
#define SCALE_CLS 7.0f
#define EPS 1e-12f

__device__ __forceinline__ float waveRed(float x){
  #pragma unroll
  for (int off = 32; off; off >>= 1) x += __shfl_xor(x, off, 64);
  return x;
}

// One block per (b,q,c) group, 512 threads (8 waves).
// LDS: sT/sR row-major [d][p] (73728 B each, stride 144 B -> b128 row reads
// at bank floor, b32 column reads ~2-way). Staged via global_load_lds w=16.
__global__ __launch_bounds__(512)
void topk_fuse(const float* __restrict__ gtrain,
               const float* __restrict__ gtest,
               const int* __restrict__ Kp,
               float* __restrict__ out)
{
  __shared__ float sT[DP];                 // test  [512][36]
  __shared__ float sR[DP];                 // train [512][36]
  __shared__ float s_tm[DD], s_rm[DD];     // row (d) means
  __shared__ __align__(16) float s_q[PP];  // test  per-pos sumsq
  __shared__ __align__(16) float s_e[PP];  // train per-pos sumsq
  __shared__ __align__(16) float s_a[PP];  // sum T*rm
  __shared__ __align__(16) float s_b[PP];  // sum R*tm
  __shared__ __align__(16) float s_wt[PP]; // fuse weights test
  __shared__ __align__(16) float s_wr[PP]; // fuse weights train
  __shared__ float s_nt[PP], s_nr[PP];     // per-pos norms
  __shared__ float s_st[PP], s_sr[PP];     // ranking scores
  __shared__ float s_red[24];

  const int t    = threadIdx.x;
  const int lane = t & 63;
  const int wave = t >> 6;                 // 0..7
  const int g    = blockIdx.x;
  const int K    = Kp[0];

  const char* gT = (const char*)(gtest  + (size_t)g * DP);
  const char* gR = (const char*)(gtrain + (size_t)g * DP);
  char* sTc = (char*)sT;
  char* sRc = (char*)sR;

  if (t < PP) { s_q[t] = 0.f; s_e[t] = 0.f; s_a[t] = 0.f; s_b[t] = 0.f; }

  // ---- Stage: issue all T chunks, then all R chunks (async DMA to LDS).
  // Per wave: 9 KiB per tensor = 9 x (64 lanes x 16 B) chunks.
  {
    const int base = wave * 9216;
    #pragma unroll
    for (int s = 0; s < 9; ++s) {
      const int off = base + s * 1024;
      __builtin_amdgcn_global_load_lds((const uint32_t*)(gT + off + lane*16),
                                       (uint32_t*)(sTc + off), 16, 0, 0);
    }
    #pragma unroll
    for (int s = 0; s < 9; ++s) {
      const int off = base + s * 1024;
      __builtin_amdgcn_global_load_lds((const uint32_t*)(gR + off + lane*16),
                                       (uint32_t*)(sRc + off), 16, 0, 0);
    }
  }

  // ---- Barrier A: T resident (the 9 R-loads stay in flight). ----
  asm volatile("s_waitcnt vmcnt(9) lgkmcnt(0)" ::: "memory");
  __builtin_amdgcn_s_barrier();
  __builtin_amdgcn_sched_barrier(0);

  // ---- Phase T1: row means of T (thread t <-> row d=t), under R-load. ----
  float tm;
  {
    const float4* r4 = (const float4*)(sT + t * PP);
    float s = 0.f;
    #pragma unroll
    for (int j = 0; j < 9; ++j) {
      float4 x = r4[j];
      s += (x.x + x.y) + (x.z + x.w);
    }
    tm = s * (1.0f / 36.0f);
    s_tm[t] = tm;
  }
  {
    float pm2 = waveRed(tm * tm);
    if (lane == 0) s_red[wave] = pm2;
  }

  // ---- Phase T2: column sumsq of T (q[p]), still under R-load. ----
  if (t < 504) {
    const int p = t % 36, c = t / 36;       // 36 cols x 14 d-chunks
    float q = 0.f;
    for (int d = c; d < DD; d += 14) { float x = sT[d*PP + p]; q += x * x; }
    atomicAdd(&s_q[p], q);
  }

  // ---- Barrier B: R resident; tm/q/m2 visible. ----
  asm volatile("s_waitcnt vmcnt(0) lgkmcnt(0)" ::: "memory");
  __builtin_amdgcn_s_barrier();
  __builtin_amdgcn_sched_barrier(0);

  // ---- Phase R1: row means of R + mean-cosine partials. ----
  float rm;
  {
    const float4* r4 = (const float4*)(sR + t * PP);
    float s = 0.f;
    #pragma unroll
    for (int j = 0; j < 9; ++j) {
      float4 x = r4[j];
      s += (x.x + x.y) + (x.z + x.w);
    }
    rm = s * (1.0f / 36.0f);
    s_rm[t] = rm;
  }
  {
    float pr2 = waveRed(rm * rm);
    float pmr = waveRed(rm * tm);           // tm is this thread's own row
    if (lane == 0) { s_red[8 + wave] = pr2; s_red[16 + wave] = pmr; }
  }
  __syncthreads();                                              // C

  // ---- Mean-cosine score (global scores). ----
  if (t == 0) {
    float m2 = 0.f, r2 = 0.f, mr = 0.f;
    #pragma unroll
    for (int w = 0; w < 8; ++w) {
      m2 += s_red[w]; r2 += s_red[8 + w]; mr += s_red[16 + w];
    }
    out[g] = SCALE_CLS * mr / (fmaxf(sqrtf(m2), EPS) * fmaxf(sqrtf(r2), EPS));
  }

  // ---- Phase C2: column dots a,e,b (needs rm/tm tables). ----
  if (t < 504) {
    const int p = t % 36, c = t / 36;
    float a = 0.f, e = 0.f, b = 0.f;
    for (int d = c; d < DD; d += 14) {
      const int i = d * PP + p;
      float x = sT[i], y = sR[i];
      a += x * s_rm[d];
      e += y * y;
      b += y * s_tm[d];
    }
    atomicAdd(&s_a[p], a); atomicAdd(&s_e[p], e); atomicAdd(&s_b[p], b);
  }
  __syncthreads();                                              // D

  // ---- Norms + ranking scores (positive group factors dropped). ----
  if (wave < 2 && lane < PP) {
    const float* qq = wave ? s_e : s_q;
    const float* dm = wave ? s_b : s_a;
    float n  = fmaxf(sqrtf(qq[lane]), EPS);
    float sc = dm[lane] / n;
    if (wave) { s_nr[lane] = n; s_sr[lane] = sc; }
    else      { s_nt[lane] = n; s_st[lane] = sc; }
  }
  __syncthreads();                                              // E1

  // ---- Top-K via ranks (jnp ties: lower index wins). ----
  if (wave < 2 && lane < PP) {
    const float* sc = wave ? s_sr : s_st;
    const float* nn = wave ? s_nr : s_nt;
    float*       w  = wave ? s_wr : s_wt;
    float mine = sc[lane];
    int rank = 0;
    #pragma unroll
    for (int p = 0; p < PP; ++p) {
      float o = sc[p];
      rank += ((o > mine) || (o == mine && p < lane)) ? 1 : 0;
    }
    w[lane] = (rank < K) ? (1.0f / nn[lane]) : 0.f;
  }
  __syncthreads();                                              // E2

  // ---- Fuse: weighted row sums (1/K cancels in l2norm) + cosine. ----
  {
    const float4* rt = (const float4*)(sT + t * PP);
    const float4* rr = (const float4*)(sR + t * PP);
    const float4* w4t = (const float4*)s_wt;
    const float4* w4r = (const float4*)s_wr;
    float U = 0.f, V = 0.f;
    #pragma unroll
    for (int j = 0; j < 9; ++j) {
      float4 x = rt[j], y = rr[j], a4 = w4t[j], b4 = w4r[j];
      U += x.x*a4.x + x.y*a4.y + x.z*a4.z + x.w*a4.w;
      V += y.x*b4.x + y.y*b4.y + y.z*b4.z + y.w*b4.w;
    }
    float u2 = waveRed(U * U);
    float v2 = waveRed(V * V);
    float uv = waveRed(U * V);
    if (lane == 0) { s_red[wave] = u2; s_red[8 + wave] = v2; s_red[16 + wave] = uv; }
  }
  __syncthreads();                                              // F
  if (t == 0) {
    float u2 = 0.f, v2 = 0.f, uv = 0.f;
    #pragma unroll
    for (int w = 0; w < 8; ++w) {
      u2 += s_red[w]; v2 += s_red[8 + w]; uv += s_red[16 + w];
    }
    out[NGRP + g] = SCALE_CLS * uv / (fmaxf(sqrtf(u2), EPS) * fmaxf(sqrtf(v2), EPS));
  }
}

extern "C" void kernel_launch(void* const* d_in, const int* in_sizes, int n_in,
                              void* d_out, int out_size, void* d_ws, size_t ws_size,
                              hipStream_t stream)
{
  const float* ftrain = (const float*)d_in[0];
  const float* ftest  = (const float*)d_in[1];
  const int*   Kp     = (const int*)d_in[2];
  float*       out    = (float*)d_out;
  topk_fuse<<<NGRP, 512, 0, stream>>>(ftrain, ftest, Kp, out);
}